// Round 10
// baseline (209.582 us; speedup 1.0000x reference)
//
#include <hip/hip_runtime.h>
#include <hip/hip_bf16.h>

#define NN 10000     // nodes
#define NE 640000    // edges
#define NG 64        // graphs
#define NF 128       // feature dim (both layers)
#define NC 10        // classes
#define TM 32        // gemm row tile
#define TKC 32       // gemm k chunk
#define NB 250       // dst buckets (40 nodes each)
#define BSZ 40       // nodes per bucket
#define G1 512       // blocks in hist/bucket passes (2 blocks/CU)
#define ECHUNK 1250  // edges per block (G1*ECHUNK == NE)

// ---------------- ws layout (bytes) ----------------
// 0        coff  (10001 int)     40016
// 40016    bbase (251 int)       1024
// 41040    dinv  (10000 f32)     40000
// 81040    csrc  (640000 int)    2560000
// 2641040  bufA  (10000*128 f32) 5120000  [bh (512KB) aliases head: dead before gemm1]
// 7761040  bufB  (10000*128 f32) 5120000  [ebuf (2.56MB) aliases head: dead before gath1]
// total ~12.9 MB; zero global atomics -> no pre-zeroing needed
//
// Math: GCN layer out[i] = relu( dinv[i]*(sum_{j->i} g[j] + g[i]) + b )
// with g[j] = dinv[j]*h[j] folded into the GEMM epilogue -> the edge gather
// needs NO per-edge weight (cw eliminated; R7-R9 carried a 2.56MB cw stream).

// Wave-uniform detection of int64 vs int32 index buffers. For little-endian
// int64, every odd 32-bit word is the (always-zero here) high half.
__device__ __forceinline__ int detect64(const int* w, long span) {
    int lane = threadIdx.x & 63;
    long e = (long)lane * (span - 1) / 63;
    return (__ballot(w[2 * e + 1] != 0) == 0ULL) ? 1 : 0;
}

__device__ __forceinline__ int ld_idx(const void* p, long i, int is64) {
    return is64 ? (int)((const long long*)p)[i] : ((const int*)p)[i];
}

// Pass A: per-block bucket histogram, stored bucket-major: bh[b*G1 + g].
__global__ __launch_bounds__(256) void k_hist(const void* __restrict__ ei,
                                              int* __restrict__ bh) {
    int is64 = detect64((const int*)ei, NE);
    __shared__ int hist[256];
    int tid = threadIdx.x;
    hist[tid] = 0;
    __syncthreads();
    int e0 = blockIdx.x * ECHUNK, e1 = min(NE, e0 + ECHUNK);
    for (int e = e0 + tid; e < e1; e += 256) {
        int dst = ld_idx(ei, (long)NE + e, is64);
        atomicAdd(&hist[dst / BSZ], 1);
    }
    __syncthreads();
    bh[tid * G1 + blockIdx.x] = hist[tid];
}

// Pass B (single block): per-bucket exclusive prefix over G1 group counts
// (wave-scan, 8 vals/lane), then bucket-base scan -> bbase.
__global__ __launch_bounds__(1024) void k_bscan(int* __restrict__ bh,
                                                int* __restrict__ bbase) {
    __shared__ int btot[256];
    __shared__ int bb[NB + 1];
    int tid = threadIdx.x, wv = tid >> 6, lane = tid & 63;
    for (int b = wv; b < NB; b += 16) {
        int base = b * G1 + lane * 8;
        int vals[8];
        int lsum = 0;
#pragma unroll
        for (int i = 0; i < 8; ++i) { vals[i] = bh[base + i]; lsum += vals[i]; }
        int pref = lsum;
        for (int o = 1; o < 64; o <<= 1) {
            int t = __shfl_up(pref, o, 64);
            if (lane >= o) pref += t;
        }
        int run = pref - lsum;              // exclusive
#pragma unroll
        for (int i = 0; i < 8; ++i) { int v = vals[i]; bh[base + i] = run; run += v; }
        if (lane == 63) btot[b] = run;
    }
    __syncthreads();
    if (tid == 0) {
        int run = 0;
        for (int b = 0; b < NB; ++b) { bb[b] = run; run += btot[b]; }
        bb[NB] = run;                        // == NE
    }
    __syncthreads();
    if (tid <= NB) bbase[tid] = bb[tid];
}

// Pass C: scatter edges to bucket regions, packed (ldst<<14)|src. Each block
// owns a CONTIGUOUS sub-range per bucket (prefix cursors) -> low write amp.
__global__ __launch_bounds__(256) void k_bucket(const void* __restrict__ ei,
                                                const int* __restrict__ bh,
                                                const int* __restrict__ bbase,
                                                int* __restrict__ ebuf) {
    int is64 = detect64((const int*)ei, NE);
    __shared__ int cur[256];
    int tid = threadIdx.x;
    if (tid < NB) cur[tid] = bh[tid * G1 + blockIdx.x] + bbase[tid];
    __syncthreads();
    int e0 = blockIdx.x * ECHUNK, e1 = min(NE, e0 + ECHUNK);
    for (int e = e0 + tid; e < e1; e += 256) {
        int dst = ld_idx(ei, (long)NE + e, is64);
        int src = ld_idx(ei, (long)e, is64);
        int b = dst / BSZ;
        int p = atomicAdd(&cur[b], 1);
        ebuf[p] = ((dst - b * BSZ) << 14) | src;
    }
}

// Pass D: one block per bucket. Count/scan 40 dsts -> coff + dinv; scatter
// csrc within the block-private contiguous region.
__global__ __launch_bounds__(256) void k_csr(const int* __restrict__ ebuf,
                                             const int* __restrict__ bbase,
                                             int* __restrict__ coff,
                                             float* __restrict__ dinv,
                                             int* __restrict__ csrc) {
    __shared__ int dcount[BSZ];
    __shared__ int dstart[BSZ];
    __shared__ int cur[BSZ];
    int b = blockIdx.x, tid = threadIdx.x;
    if (tid < BSZ) dcount[tid] = 0;
    __syncthreads();
    int base = bbase[b], end = bbase[b + 1];
    for (int i = base + tid; i < end; i += 256)
        atomicAdd(&dcount[ebuf[i] >> 14], 1);
    __syncthreads();
    if (tid == 0) {
        int run = 0;
        for (int i = 0; i < BSZ; ++i) {
            dstart[i] = run; cur[i] = base + run; run += dcount[i];
        }
    }
    __syncthreads();
    if (tid < BSZ) {
        coff[b * BSZ + tid] = base + dstart[tid];
        dinv[b * BSZ + tid] = rsqrtf((float)dcount[tid] + 1.0f);
    }
    if (b == NB - 1 && tid == 0) coff[NN] = NE;
    __syncthreads();
    for (int i = base + tid; i < end; i += 256) {
        int pk = ebuf[i];
        int p = atomicAdd(&cur[pk >> 14], 1);
        csrc[p] = pk & 16383;
    }
}

// Y = (X @ W) * dinv[row], register-tiled. Block: 256 thr, 32 rows x 128 cols;
// 4x4 acc. The dinv row-scale in the epilogue is what lets the gather run
// weight-free.
__global__ __launch_bounds__(256) void k_gemm(const float* __restrict__ X,
                                              const float* __restrict__ W,
                                              const float* __restrict__ dinv,
                                              float* __restrict__ Y, int nrows) {
    __shared__ float sX[TKC * 36];       // 4.6 KB
    __shared__ float sW[32 * 132];       // 16.9 KB
    int tid = threadIdx.x;
    int rg = tid & 7;                    // rows rg*4 .. rg*4+3
    int cg = tid >> 3;                   // cols cg*4 .. cg*4+3 (0..31)
    int m0 = blockIdx.x * TM;
    float acc[4][4] = {{0.f}};
    for (int kc = 0; kc < NF / TKC; ++kc) {
        int k0 = kc * TKC;
        {   // stage X^T (one float4 per thread)
            int row = tid >> 3, kq = tid & 7;
            int mm = m0 + row; if (mm > nrows - 1) mm = nrows - 1;
            float4 v = *(const float4*)(X + (size_t)mm * NF + k0 + kq * 4);
            sX[(kq * 4 + 0) * 36 + row] = v.x;
            sX[(kq * 4 + 1) * 36 + row] = v.y;
            sX[(kq * 4 + 2) * 36 + row] = v.z;
            sX[(kq * 4 + 3) * 36 + row] = v.w;
        }
#pragma unroll
        for (int j = 0; j < 4; ++j) {    // stage W panels (4 float4 per thread)
            int idx = tid + 256 * j;
            int k = idx >> 5, cq = idx & 31;
            float4 v = *(const float4*)(W + (size_t)(k0 + k) * NF + cq * 4);
            *(float4*)(sW + cq * 132 + k * 4) = v;
        }
        __syncthreads();
#pragma unroll 8
        for (int k = 0; k < TKC; ++k) {
            float4 xf = *(const float4*)(sX + k * 36 + rg * 4);
            float4 wf = *(const float4*)(sW + cg * 132 + k * 4);
            acc[0][0] = fmaf(xf.x, wf.x, acc[0][0]);
            acc[0][1] = fmaf(xf.x, wf.y, acc[0][1]);
            acc[0][2] = fmaf(xf.x, wf.z, acc[0][2]);
            acc[0][3] = fmaf(xf.x, wf.w, acc[0][3]);
            acc[1][0] = fmaf(xf.y, wf.x, acc[1][0]);
            acc[1][1] = fmaf(xf.y, wf.y, acc[1][1]);
            acc[1][2] = fmaf(xf.y, wf.z, acc[1][2]);
            acc[1][3] = fmaf(xf.y, wf.w, acc[1][3]);
            acc[2][0] = fmaf(xf.z, wf.x, acc[2][0]);
            acc[2][1] = fmaf(xf.z, wf.y, acc[2][1]);
            acc[2][2] = fmaf(xf.z, wf.z, acc[2][2]);
            acc[2][3] = fmaf(xf.z, wf.w, acc[2][3]);
            acc[3][0] = fmaf(xf.w, wf.x, acc[3][0]);
            acc[3][1] = fmaf(xf.w, wf.y, acc[3][1]);
            acc[3][2] = fmaf(xf.w, wf.z, acc[3][2]);
            acc[3][3] = fmaf(xf.w, wf.w, acc[3][3]);
        }
        __syncthreads();
    }
#pragma unroll
    for (int r = 0; r < 4; ++r) {
        int m = m0 + rg * 4 + r;
        if (m < nrows) {
            float ds = dinv[m];
            *(float4*)(Y + (size_t)m * NF + cg * 4) =
                make_float4(acc[r][0] * ds, acc[r][1] * ds,
                            acc[r][2] * ds, acc[r][3] * ds);
        }
    }
}

// OUT[n] = relu( dinv[n]*( sum_e G[csrc[e]] + G[n] ) + bias ), G pre-scaled.
// One wave per node; half-wave (32 lanes x float4 = 512B) per edge; 4-deep
// unroll -> 8 independent row reads in flight per wave (R7-proven shape).
__global__ __launch_bounds__(256) void k_gather(const float* __restrict__ G,
                                                const int* __restrict__ off,
                                                const int* __restrict__ csrc,
                                                const float* __restrict__ dinv,
                                                const float* __restrict__ bias,
                                                float* __restrict__ OUT) {
    int wid = threadIdx.x >> 6, lane = threadIdx.x & 63;
    int half = lane >> 5;
    int c4 = lane & 31;
    int n = blockIdx.x * 4 + wid;
    if (n >= NN) return;
    int beg = off[n], end = off[n + 1];
    float din = dinv[n];
    float4 acc = make_float4(0.f, 0.f, 0.f, 0.f);
    int e = beg + half;
    for (; e + 6 < end; e += 8) {
        int s0 = csrc[e];
        int s1 = csrc[e + 2];
        int s2 = csrc[e + 4];
        int s3 = csrc[e + 6];
        float4 v0 = ((const float4*)(G + (size_t)s0 * NF))[c4];
        float4 v1 = ((const float4*)(G + (size_t)s1 * NF))[c4];
        float4 v2 = ((const float4*)(G + (size_t)s2 * NF))[c4];
        float4 v3 = ((const float4*)(G + (size_t)s3 * NF))[c4];
        acc.x += v0.x; acc.y += v0.y; acc.z += v0.z; acc.w += v0.w;
        acc.x += v1.x; acc.y += v1.y; acc.z += v1.z; acc.w += v1.w;
        acc.x += v2.x; acc.y += v2.y; acc.z += v2.z; acc.w += v2.w;
        acc.x += v3.x; acc.y += v3.y; acc.z += v3.z; acc.w += v3.w;
    }
    for (; e < end; e += 2) {
        int s = csrc[e];
        float4 v = ((const float4*)(G + (size_t)s * NF))[c4];
        acc.x += v.x; acc.y += v.y; acc.z += v.z; acc.w += v.w;
    }
    acc.x += __shfl_xor(acc.x, 32);
    acc.y += __shfl_xor(acc.y, 32);
    acc.z += __shfl_xor(acc.z, 32);
    acc.w += __shfl_xor(acc.w, 32);
    if (half == 0) {
        float4 sv = ((const float4*)(G + (size_t)n * NF))[c4];
        float4 bb = ((const float4*)bias)[c4];
        float4 o;
        o.x = fmaxf(fmaf(din, acc.x + sv.x, bb.x), 0.f);
        o.y = fmaxf(fmaf(din, acc.y + sv.y, bb.y), 0.f);
        o.z = fmaxf(fmaf(din, acc.z + sv.z, bb.z), 0.f);
        o.w = fmaxf(fmaf(din, acc.w + sv.w, bb.w), 0.f);
        ((float4*)(OUT + (size_t)n * NF))[c4] = o;
    }
}

// Fused global-mean-pool + final linear (batch is sorted -> contiguous ranges).
__global__ __launch_bounds__(256) void k_poolfin(const float* __restrict__ H,
                                                 const void* __restrict__ batch,
                                                 const float* __restrict__ Wl,
                                                 const float* __restrict__ bl,
                                                 float* __restrict__ out) {
    int is64 = detect64((const int*)batch, NN / 2);
    __shared__ int sb[2];
    __shared__ float4 part[256];
    __shared__ float pooled[NF];
    int g = blockIdx.x;
    int tid = threadIdx.x;
    if (tid < 2) {
        int target = g + tid;                 // lower_bound(batch, target)
        int lo = 0, hi = NN;
        while (lo < hi) {
            int mid = (lo + hi) >> 1;
            if (ld_idx(batch, mid, is64) < target) lo = mid + 1; else hi = mid;
        }
        sb[tid] = lo;
    }
    __syncthreads();
    int beg = sb[0], end = sb[1];
    int c4 = tid & 31, r = tid >> 5;          // 8 rows in flight
    float4 acc = make_float4(0.f, 0.f, 0.f, 0.f);
    for (int n = beg + r; n < end; n += 8) {
        float4 v = ((const float4*)(H + (size_t)n * NF))[c4];
        acc.x += v.x; acc.y += v.y; acc.z += v.z; acc.w += v.w;
    }
    part[tid] = acc;
    __syncthreads();
    if (tid < 32) {
        float4 s = part[tid];
#pragma unroll
        for (int j = 1; j < 8; j++) {
            float4 p = part[tid + 32 * j];
            s.x += p.x; s.y += p.y; s.z += p.z; s.w += p.w;
        }
        float ic = 1.0f / fmaxf((float)(end - beg), 1.0f);
        pooled[tid * 4 + 0] = s.x * ic;
        pooled[tid * 4 + 1] = s.y * ic;
        pooled[tid * 4 + 2] = s.z * ic;
        pooled[tid * 4 + 3] = s.w * ic;
    }
    __syncthreads();
    if (tid < NC) {
        float a = bl[tid];
#pragma unroll 8
        for (int k = 0; k < NF; k++)
            a = fmaf(pooled[k], Wl[k * NC + tid], a);
        out[g * NC + tid] = a;
    }
}

extern "C" void kernel_launch(void* const* d_in, const int* in_sizes, int n_in,
                              void* d_out, int out_size, void* d_ws, size_t ws_size,
                              hipStream_t stream) {
    const float* x  = (const float*)d_in[0];
    const void*  ei = d_in[1];
    const void*  bt = d_in[2];
    const float* W1 = (const float*)d_in[3];
    const float* b1 = (const float*)d_in[4];
    const float* W2 = (const float*)d_in[5];
    const float* b2 = (const float*)d_in[6];
    const float* Wl = (const float*)d_in[7];
    const float* bl = (const float*)d_in[8];

    char* ws = (char*)d_ws;
    int*   coff  = (int*)(ws + 0);
    int*   bbase = (int*)(ws + 40016);
    float* dinv  = (float*)(ws + 41040);
    int*   csrc  = (int*)(ws + 81040);
    float* bufA  = (float*)(ws + 2641040);
    float* bufB  = (float*)(ws + 7761040);
    int*   bh    = (int*)bufA;     // 512 KB scratch, dead before k_gemm #1
    int*   ebuf  = (int*)bufB;     // 2.56 MB scratch, dead before k_gather #1

    k_hist  <<<G1, 256, 0, stream>>>(ei, bh);
    k_bscan <<<1, 1024, 0, stream>>>(bh, bbase);
    k_bucket<<<G1, 256, 0, stream>>>(ei, bh, bbase, ebuf);
    k_csr   <<<NB, 256, 0, stream>>>(ebuf, bbase, coff, dinv, csrc);

    k_gemm<<<(NN + TM - 1) / TM, 256, 0, stream>>>(x, W1, dinv, bufA, NN);
    k_gather<<<(NN + 3) / 4, 256, 0, stream>>>(bufA, coff, csrc, dinv, b1, bufB);
    k_gemm<<<(NN + TM - 1) / TM, 256, 0, stream>>>(bufB, W2, dinv, bufA, NN);
    k_gather<<<(NN + 3) / 4, 256, 0, stream>>>(bufA, coff, csrc, dinv, b2, bufB);

    k_poolfin<<<NG, 256, 0, stream>>>(bufB, bt, Wl, bl, (float*)d_out);
}

// Round 11
// 195.489 us; speedup vs baseline: 1.0721x; 1.0721x over previous
//
#include <hip/hip_runtime.h>
#include <hip/hip_bf16.h>

#define NN 10000     // nodes
#define NE 640000    // edges
#define NG 64        // graphs
#define NF 128       // feature dim (both layers)
#define NC 10        // classes
#define TM 32        // gemm row tile
#define TKC 32       // gemm k chunk
#define NB 250       // dst buckets (40 nodes each)
#define BSZ 40       // nodes per bucket
#define G1 512       // blocks in hist/bucket passes (2 blocks/CU)
#define ECHUNK 1250  // edges per block (G1*ECHUNK == NE)

// ---------------- ws layout (bytes) ----------------
// 0        coff  (10001 int)     40016
// 40016    bbase (251 int)       1024
// 41040    btot  (250 int)       1024
// 42064    dinv  (10000 f32)     40000
// 82064    csrc  (640000 int)    2560000
// 2642064  bufA  (10000*128 f32) 5120000  [bh (512KB) aliases head: dead before gemm1]
// 7762064  bufB  (10000*128 f32) 5120000  [ebuf (2.56MB) aliases head: dead before gath1]
// total ~12.9 MB; zero global atomics -> no pre-zeroing needed
//
// Math: GCN layer out[i] = relu( dinv[i]*(sum_{j->i} g[j] + g[i]) + b )
// with g[j] = dinv[j]*h[j] folded into the GEMM epilogue -> the edge gather
// is weight-free (no cw array/stream).

// Wave-uniform detection of int64 vs int32 index buffers. For little-endian
// int64, every odd 32-bit word is the (always-zero here) high half.
__device__ __forceinline__ int detect64(const int* w, long span) {
    int lane = threadIdx.x & 63;
    long e = (long)lane * (span - 1) / 63;
    return (__ballot(w[2 * e + 1] != 0) == 0ULL) ? 1 : 0;
}

__device__ __forceinline__ int ld_idx(const void* p, long i, int is64) {
    return is64 ? (int)((const long long*)p)[i] : ((const int*)p)[i];
}

// Pass A: per-block bucket histogram, stored bucket-major: bh[b*G1 + g].
__global__ __launch_bounds__(256) void k_hist(const void* __restrict__ ei,
                                              int* __restrict__ bh) {
    int is64 = detect64((const int*)ei, NE);
    __shared__ int hist[256];
    int tid = threadIdx.x;
    hist[tid] = 0;
    __syncthreads();
    int e0 = blockIdx.x * ECHUNK, e1 = min(NE, e0 + ECHUNK);
    for (int e = e0 + tid; e < e1; e += 256) {
        int dst = ld_idx(ei, (long)NE + e, is64);
        atomicAdd(&hist[dst / BSZ], 1);
    }
    __syncthreads();
    bh[tid * G1 + blockIdx.x] = hist[tid];
}

// Pass B1: per-bucket exclusive prefix over the G1 group counts, PARALLEL
// across 63 blocks (one wave per bucket; 8 vals/lane + shfl wave scan).
// R10's merged single-block version serialized 512KB on one CU (~12us).
__global__ __launch_bounds__(256) void k_bscan1(int* __restrict__ bh,
                                                int* __restrict__ btot) {
    int w = blockIdx.x * 4 + (threadIdx.x >> 6);
    if (w >= NB) return;
    int lane = threadIdx.x & 63;
    int base = w * G1 + lane * 8;
    int vals[8];
    int lsum = 0;
#pragma unroll
    for (int i = 0; i < 8; ++i) { vals[i] = bh[base + i]; lsum += vals[i]; }
    int pref = lsum;
    for (int o = 1; o < 64; o <<= 1) {
        int t = __shfl_up(pref, o, 64);
        if (lane >= o) pref += t;
    }
    int run = pref - lsum;                  // exclusive
#pragma unroll
    for (int i = 0; i < 8; ++i) { int v = vals[i]; bh[base + i] = run; run += v; }
    if (lane == 63) btot[w] = run;
}

// Pass B2: scan 250 bucket totals -> bbase (tiny).
__global__ __launch_bounds__(256) void k_bscan2(const int* __restrict__ btot,
                                                int* __restrict__ bbase) {
    __shared__ int s[256];
    int tid = threadIdx.x;
    s[tid] = (tid < NB) ? btot[tid] : 0;
    __syncthreads();
    if (tid == 0) {
        int run = 0;
        for (int b = 0; b < NB; ++b) { int v = s[b]; s[b] = run; run += v; }
    }
    __syncthreads();
    if (tid < NB) bbase[tid] = s[tid];
    if (tid == 0) bbase[NB] = NE;
}

// Pass C: scatter edges to bucket regions, packed (ldst<<14)|src. Each block
// owns a CONTIGUOUS sub-range per bucket (prefix cursors) -> low write amp.
__global__ __launch_bounds__(256) void k_bucket(const void* __restrict__ ei,
                                                const int* __restrict__ bh,
                                                const int* __restrict__ bbase,
                                                int* __restrict__ ebuf) {
    int is64 = detect64((const int*)ei, NE);
    __shared__ int cur[256];
    int tid = threadIdx.x;
    if (tid < NB) cur[tid] = bh[tid * G1 + blockIdx.x] + bbase[tid];
    __syncthreads();
    int e0 = blockIdx.x * ECHUNK, e1 = min(NE, e0 + ECHUNK);
    for (int e = e0 + tid; e < e1; e += 256) {
        int dst = ld_idx(ei, (long)NE + e, is64);
        int src = ld_idx(ei, (long)e, is64);
        int b = dst / BSZ;
        int p = atomicAdd(&cur[b], 1);
        ebuf[p] = ((dst - b * BSZ) << 14) | src;
    }
}

// Pass D: one block per bucket. Count/scan 40 dsts -> coff + dinv; scatter
// csrc within the block-private contiguous region.
__global__ __launch_bounds__(256) void k_csr(const int* __restrict__ ebuf,
                                             const int* __restrict__ bbase,
                                             int* __restrict__ coff,
                                             float* __restrict__ dinv,
                                             int* __restrict__ csrc) {
    __shared__ int dcount[BSZ];
    __shared__ int dstart[BSZ];
    __shared__ int cur[BSZ];
    int b = blockIdx.x, tid = threadIdx.x;
    if (tid < BSZ) dcount[tid] = 0;
    __syncthreads();
    int base = bbase[b], end = bbase[b + 1];
    for (int i = base + tid; i < end; i += 256)
        atomicAdd(&dcount[ebuf[i] >> 14], 1);
    __syncthreads();
    if (tid == 0) {
        int run = 0;
        for (int i = 0; i < BSZ; ++i) {
            dstart[i] = run; cur[i] = base + run; run += dcount[i];
        }
    }
    __syncthreads();
    if (tid < BSZ) {
        coff[b * BSZ + tid] = base + dstart[tid];
        dinv[b * BSZ + tid] = rsqrtf((float)dcount[tid] + 1.0f);
    }
    if (b == NB - 1 && tid == 0) coff[NN] = NE;
    __syncthreads();
    for (int i = base + tid; i < end; i += 256) {
        int pk = ebuf[i];
        int p = atomicAdd(&cur[pk >> 14], 1);
        csrc[p] = pk & 16383;
    }
}

// Y = (X @ W) * dinv[row], register-tiled. Block: 256 thr, 32 rows x 128 cols;
// 4x4 acc. The dinv row-scale in the epilogue makes the gather weight-free.
__global__ __launch_bounds__(256) void k_gemm(const float* __restrict__ X,
                                              const float* __restrict__ W,
                                              const float* __restrict__ dinv,
                                              float* __restrict__ Y, int nrows) {
    __shared__ float sX[TKC * 36];       // 4.6 KB
    __shared__ float sW[32 * 132];       // 16.9 KB
    int tid = threadIdx.x;
    int rg = tid & 7;                    // rows rg*4 .. rg*4+3
    int cg = tid >> 3;                   // cols cg*4 .. cg*4+3 (0..31)
    int m0 = blockIdx.x * TM;
    float acc[4][4] = {{0.f}};
    for (int kc = 0; kc < NF / TKC; ++kc) {
        int k0 = kc * TKC;
        {   // stage X^T (one float4 per thread)
            int row = tid >> 3, kq = tid & 7;
            int mm = m0 + row; if (mm > nrows - 1) mm = nrows - 1;
            float4 v = *(const float4*)(X + (size_t)mm * NF + k0 + kq * 4);
            sX[(kq * 4 + 0) * 36 + row] = v.x;
            sX[(kq * 4 + 1) * 36 + row] = v.y;
            sX[(kq * 4 + 2) * 36 + row] = v.z;
            sX[(kq * 4 + 3) * 36 + row] = v.w;
        }
#pragma unroll
        for (int j = 0; j < 4; ++j) {    // stage W panels (4 float4 per thread)
            int idx = tid + 256 * j;
            int k = idx >> 5, cq = idx & 31;
            float4 v = *(const float4*)(W + (size_t)(k0 + k) * NF + cq * 4);
            *(float4*)(sW + cq * 132 + k * 4) = v;
        }
        __syncthreads();
#pragma unroll 8
        for (int k = 0; k < TKC; ++k) {
            float4 xf = *(const float4*)(sX + k * 36 + rg * 4);
            float4 wf = *(const float4*)(sW + cg * 132 + k * 4);
            acc[0][0] = fmaf(xf.x, wf.x, acc[0][0]);
            acc[0][1] = fmaf(xf.x, wf.y, acc[0][1]);
            acc[0][2] = fmaf(xf.x, wf.z, acc[0][2]);
            acc[0][3] = fmaf(xf.x, wf.w, acc[0][3]);
            acc[1][0] = fmaf(xf.y, wf.x, acc[1][0]);
            acc[1][1] = fmaf(xf.y, wf.y, acc[1][1]);
            acc[1][2] = fmaf(xf.y, wf.z, acc[1][2]);
            acc[1][3] = fmaf(xf.y, wf.w, acc[1][3]);
            acc[2][0] = fmaf(xf.z, wf.x, acc[2][0]);
            acc[2][1] = fmaf(xf.z, wf.y, acc[2][1]);
            acc[2][2] = fmaf(xf.z, wf.z, acc[2][2]);
            acc[2][3] = fmaf(xf.z, wf.w, acc[2][3]);
            acc[3][0] = fmaf(xf.w, wf.x, acc[3][0]);
            acc[3][1] = fmaf(xf.w, wf.y, acc[3][1]);
            acc[3][2] = fmaf(xf.w, wf.z, acc[3][2]);
            acc[3][3] = fmaf(xf.w, wf.w, acc[3][3]);
        }
        __syncthreads();
    }
#pragma unroll
    for (int r = 0; r < 4; ++r) {
        int m = m0 + rg * 4 + r;
        if (m < nrows) {
            float ds = dinv[m];
            *(float4*)(Y + (size_t)m * NF + cg * 4) =
                make_float4(acc[r][0] * ds, acc[r][1] * ds,
                            acc[r][2] * ds, acc[r][3] * ds);
        }
    }
}

// OUT[n] = relu( dinv[n]*( sum_e G[csrc[e]] + G[n] ) + bias ), G pre-scaled.
// One wave per node; half-wave (32 lanes x float4 = 512B) per edge; 4-deep
// unroll -> 8 independent row reads in flight per wave (R7-proven shape;
// R8 split / R9 unroll-8 / R10 cw-free all confirmed the ~9.3 TB/s cap).
__global__ __launch_bounds__(256) void k_gather(const float* __restrict__ G,
                                                const int* __restrict__ off,
                                                const int* __restrict__ csrc,
                                                const float* __restrict__ dinv,
                                                const float* __restrict__ bias,
                                                float* __restrict__ OUT) {
    int wid = threadIdx.x >> 6, lane = threadIdx.x & 63;
    int half = lane >> 5;
    int c4 = lane & 31;
    int n = blockIdx.x * 4 + wid;
    if (n >= NN) return;
    int beg = off[n], end = off[n + 1];
    float din = dinv[n];
    float4 acc = make_float4(0.f, 0.f, 0.f, 0.f);
    int e = beg + half;
    for (; e + 6 < end; e += 8) {
        int s0 = csrc[e];
        int s1 = csrc[e + 2];
        int s2 = csrc[e + 4];
        int s3 = csrc[e + 6];
        float4 v0 = ((const float4*)(G + (size_t)s0 * NF))[c4];
        float4 v1 = ((const float4*)(G + (size_t)s1 * NF))[c4];
        float4 v2 = ((const float4*)(G + (size_t)s2 * NF))[c4];
        float4 v3 = ((const float4*)(G + (size_t)s3 * NF))[c4];
        acc.x += v0.x; acc.y += v0.y; acc.z += v0.z; acc.w += v0.w;
        acc.x += v1.x; acc.y += v1.y; acc.z += v1.z; acc.w += v1.w;
        acc.x += v2.x; acc.y += v2.y; acc.z += v2.z; acc.w += v2.w;
        acc.x += v3.x; acc.y += v3.y; acc.z += v3.z; acc.w += v3.w;
    }
    for (; e < end; e += 2) {
        int s = csrc[e];
        float4 v = ((const float4*)(G + (size_t)s * NF))[c4];
        acc.x += v.x; acc.y += v.y; acc.z += v.z; acc.w += v.w;
    }
    acc.x += __shfl_xor(acc.x, 32);
    acc.y += __shfl_xor(acc.y, 32);
    acc.z += __shfl_xor(acc.z, 32);
    acc.w += __shfl_xor(acc.w, 32);
    if (half == 0) {
        float4 sv = ((const float4*)(G + (size_t)n * NF))[c4];
        float4 bb = ((const float4*)bias)[c4];
        float4 o;
        o.x = fmaxf(fmaf(din, acc.x + sv.x, bb.x), 0.f);
        o.y = fmaxf(fmaf(din, acc.y + sv.y, bb.y), 0.f);
        o.z = fmaxf(fmaf(din, acc.z + sv.z, bb.z), 0.f);
        o.w = fmaxf(fmaf(din, acc.w + sv.w, bb.w), 0.f);
        ((float4*)(OUT + (size_t)n * NF))[c4] = o;
    }
}

// Fused global-mean-pool + final linear (batch is sorted -> contiguous ranges).
__global__ __launch_bounds__(256) void k_poolfin(const float* __restrict__ H,
                                                 const void* __restrict__ batch,
                                                 const float* __restrict__ Wl,
                                                 const float* __restrict__ bl,
                                                 float* __restrict__ out) {
    int is64 = detect64((const int*)batch, NN / 2);
    __shared__ int sb[2];
    __shared__ float4 part[256];
    __shared__ float pooled[NF];
    int g = blockIdx.x;
    int tid = threadIdx.x;
    if (tid < 2) {
        int target = g + tid;                 // lower_bound(batch, target)
        int lo = 0, hi = NN;
        while (lo < hi) {
            int mid = (lo + hi) >> 1;
            if (ld_idx(batch, mid, is64) < target) lo = mid + 1; else hi = mid;
        }
        sb[tid] = lo;
    }
    __syncthreads();
    int beg = sb[0], end = sb[1];
    int c4 = tid & 31, r = tid >> 5;          // 8 rows in flight
    float4 acc = make_float4(0.f, 0.f, 0.f, 0.f);
    for (int n = beg + r; n < end; n += 8) {
        float4 v = ((const float4*)(H + (size_t)n * NF))[c4];
        acc.x += v.x; acc.y += v.y; acc.z += v.z; acc.w += v.w;
    }
    part[tid] = acc;
    __syncthreads();
    if (tid < 32) {
        float4 s = part[tid];
#pragma unroll
        for (int j = 1; j < 8; j++) {
            float4 p = part[tid + 32 * j];
            s.x += p.x; s.y += p.y; s.z += p.z; s.w += p.w;
        }
        float ic = 1.0f / fmaxf((float)(end - beg), 1.0f);
        pooled[tid * 4 + 0] = s.x * ic;
        pooled[tid * 4 + 1] = s.y * ic;
        pooled[tid * 4 + 2] = s.z * ic;
        pooled[tid * 4 + 3] = s.w * ic;
    }
    __syncthreads();
    if (tid < NC) {
        float a = bl[tid];
#pragma unroll 8
        for (int k = 0; k < NF; k++)
            a = fmaf(pooled[k], Wl[k * NC + tid], a);
        out[g * NC + tid] = a;
    }
}

extern "C" void kernel_launch(void* const* d_in, const int* in_sizes, int n_in,
                              void* d_out, int out_size, void* d_ws, size_t ws_size,
                              hipStream_t stream) {
    const float* x  = (const float*)d_in[0];
    const void*  ei = d_in[1];
    const void*  bt = d_in[2];
    const float* W1 = (const float*)d_in[3];
    const float* b1 = (const float*)d_in[4];
    const float* W2 = (const float*)d_in[5];
    const float* b2 = (const float*)d_in[6];
    const float* Wl = (const float*)d_in[7];
    const float* bl = (const float*)d_in[8];

    char* ws = (char*)d_ws;
    int*   coff  = (int*)(ws + 0);
    int*   bbase = (int*)(ws + 40016);
    int*   btot  = (int*)(ws + 41040);
    float* dinv  = (float*)(ws + 42064);
    int*   csrc  = (int*)(ws + 82064);
    float* bufA  = (float*)(ws + 2642064);
    float* bufB  = (float*)(ws + 7762064);
    int*   bh    = (int*)bufA;     // 512 KB scratch, dead before k_gemm #1
    int*   ebuf  = (int*)bufB;     // 2.56 MB scratch, dead before k_gather #1

    k_hist  <<<G1, 256, 0, stream>>>(ei, bh);
    k_bscan1<<<(NB + 3) / 4, 256, 0, stream>>>(bh, btot);
    k_bscan2<<<1, 256, 0, stream>>>(btot, bbase);
    k_bucket<<<G1, 256, 0, stream>>>(ei, bh, bbase, ebuf);
    k_csr   <<<NB, 256, 0, stream>>>(ebuf, bbase, coff, dinv, csrc);

    k_gemm<<<(NN + TM - 1) / TM, 256, 0, stream>>>(x, W1, dinv, bufA, NN);
    k_gather<<<(NN + 3) / 4, 256, 0, stream>>>(bufA, coff, csrc, dinv, b1, bufB);
    k_gemm<<<(NN + TM - 1) / TM, 256, 0, stream>>>(bufB, W2, dinv, bufA, NN);
    k_gather<<<(NN + 3) / 4, 256, 0, stream>>>(bufA, coff, csrc, dinv, b2, bufB);

    k_poolfin<<<NG, 256, 0, stream>>>(bufB, bt, Wl, bl, (float*)d_out);
}